// Round 1
// baseline (656.792 us; speedup 1.0000x reference)
//
#include <hip/hip_runtime.h>
#include <stdint.h>

typedef unsigned short u16;
typedef __bf16 bf16x8 __attribute__((ext_vector_type(8)));
typedef float floatx4 __attribute__((ext_vector_type(4)));

#define DEVI static __device__ __forceinline__

DEVI u16 f2bf(float f) {
  uint32_t u = __builtin_bit_cast(uint32_t, f);
  u += 0x7FFFu + ((u >> 16) & 1u);
  return (u16)(u >> 16);
}
DEVI float bf2f(u16 b) {
  return __builtin_bit_cast(float, (uint32_t)b << 16);
}

// ---- workspace layout (bytes) ----
static constexpr size_t SZ_SATT   = (size_t)8*4*96*96*8*2;   // bf16 [m][cb][y][x][c8]
static constexpr size_t SZ_GRDT   = (size_t)4*32*32*8*8*2;   // bf16 [cb][i][j][n][c8]
static constexpr size_t OFF_SATT_H = 0;
static constexpr size_t OFF_SATT_L = OFF_SATT_H + SZ_SATT;
static constexpr size_t OFF_GRDT_H = OFF_SATT_L + SZ_SATT;
static constexpr size_t OFF_GRDT_L = OFF_GRDT_H + SZ_GRDT;
static constexpr size_t OFF_CORR   = OFF_GRDT_L + SZ_GRDT;          // f32 [m][n][65][65]
static constexpr size_t OFF_S2     = OFF_CORR + (size_t)270400*4;   // f32 [m][96][96]
static constexpr size_t OFF_HS     = OFF_S2   + (size_t)73728*4;    // f32 [m][96][65]
static constexpr size_t OFF_PART   = OFF_HS   + (size_t)49920*4;    // f32 [m][65][65]
static constexpr size_t OFF_NRM    = OFF_PART + (size_t)33800*4;    // f32 grd_nrm2[8], sat_nrm2[8]
static constexpr size_t OFF_MASK   = OFF_NRM  + 256;                // f32 [n][1024]
static constexpr size_t OFF_POS    = OFF_MASK + (size_t)8192*4;     // int ph/pw per n (16 ints)

// ---- K1: sat slice -> bf16 hi/lo channels-last + s2 + sat norm ----
__global__ void k_sat(const float* __restrict__ sat, u16* __restrict__ sTh,
                      u16* __restrict__ sTl, float* __restrict__ s2,
                      float* __restrict__ snrm2) {
  const int gid = blockIdx.x * 256 + threadIdx.x;      // 73728 threads exactly
  const int m = gid / 9216;
  const int rem = gid - m * 9216;
  const int y = rem / 96;
  const int x = rem - y * 96;
  const float* src = sat + ((size_t)m*32*128 + (y+16))*128 + (x+16);
  float vals[32]; float ss = 0.f;
  #pragma unroll
  for (int c = 0; c < 32; ++c) {
    float v = src[(size_t)c * 16384];
    vals[c] = v; ss += v*v;
  }
  s2[gid] = ss;
  #pragma unroll
  for (int cb = 0; cb < 4; ++cb) {
    union { u16 us[8]; uint4 v4; } ph, pl;
    #pragma unroll
    for (int e = 0; e < 8; ++e) {
      float v = vals[cb*8+e];
      u16 h = f2bf(v);
      ph.us[e] = h;
      pl.us[e] = f2bf(v - bf2f(h));
    }
    size_t o = ((size_t)(m*4+cb)*9216 + rem)*8;
    *(uint4*)(&sTh[o]) = ph.v4;
    *(uint4*)(&sTl[o]) = pl.v4;
  }
  __shared__ float red[256];
  red[threadIdx.x] = ss; __syncthreads();
  for (int s = 128; s > 0; s >>= 1) {
    if (threadIdx.x < s) red[threadIdx.x] += red[threadIdx.x + s];
    __syncthreads();
  }
  if (threadIdx.x == 0) atomicAdd(&snrm2[m], red[0]);
}

// ---- K2: grd -> bf16 hi/lo [cb][i][j][n][c8] + norm + channel-sum mask ----
__global__ void k_grd(const float* __restrict__ grd, u16* __restrict__ gTh,
                      u16* __restrict__ gTl, float* __restrict__ gnrm2,
                      float* __restrict__ gmask) {
  const int n = blockIdx.x, t = threadIdx.x;
  float nrm = 0.f, scs[4];
  #pragma unroll
  for (int it = 0; it < 4; ++it) {
    const int pidx = it*256 + t;                  // pidx = i*32 + j
    float vals[32]; float sc = 0.f;
    #pragma unroll
    for (int c = 0; c < 32; ++c) {
      float v = grd[((size_t)n*32 + c)*1024 + pidx];
      vals[c] = v; sc += v; nrm += v*v;
    }
    scs[it] = sc;
    #pragma unroll
    for (int cb = 0; cb < 4; ++cb) {
      union { u16 us[8]; uint4 v4; } ph, pl;
      #pragma unroll
      for (int e = 0; e < 8; ++e) {
        float v = vals[cb*8+e];
        u16 h = f2bf(v); ph.us[e] = h; pl.us[e] = f2bf(v - bf2f(h));
      }
      size_t o = (size_t)cb*65536 + (size_t)pidx*64 + (size_t)n*8;
      *(uint4*)(&gTh[o]) = ph.v4;
      *(uint4*)(&gTl[o]) = pl.v4;
    }
  }
  __shared__ float red[256];
  red[t] = nrm; __syncthreads();
  for (int s = 128; s > 0; s >>= 1) { if (t < s) red[t] += red[t+s]; __syncthreads(); }
  const float gn = fmaxf(sqrtf(red[0]), 1e-12f);
  if (t == 0) gnrm2[n] = red[0];
  const float thr = 1e-6f * gn;   // |sum_c grd / gn| > 1e-6
  #pragma unroll
  for (int it = 0; it < 4; ++it)
    gmask[n*1024 + it*256 + t] = (fabsf(scs[it]) > thr) ? 1.f : 0.f;
}

// ---- K3/K4: separable 32x32 window sum of s2 ----
__global__ void k_hs(const float* __restrict__ s2, float* __restrict__ hs) {
  const int gid = blockIdx.x*256 + threadIdx.x;   // 49920 exactly
  const int m = gid / 6240;
  const int rem = gid - m*6240;
  const int y = rem / 65;
  const int xo = rem - y*65;
  const float* r = s2 + ((size_t)m*96 + y)*96 + xo;
  float s = 0.f;
  #pragma unroll
  for (int j = 0; j < 32; ++j) s += r[j];
  hs[gid] = s;
}

__global__ void k_part(const float* __restrict__ hs, float* __restrict__ part) {
  const int gid = blockIdx.x*256 + threadIdx.x;
  if (gid >= 33800) return;
  const int m = gid / 4225;
  const int rem = gid - m*4225;
  const int yo = rem / 65;
  const int xo = rem - yo*65;
  const float* c = hs + (size_t)m*6240 + yo*65 + xo;
  float s = 0.f;
  #pragma unroll
  for (int i = 0; i < 32; ++i) s += c[(size_t)i*65];
  part[gid] = s;
}

// ---- K5: the conv. block = 1 wave = (m, 5 y-rows, 16 x-cols, all n). ----
// 3-term bf16 split MFMA; A slides over filter-row i in registers.
__global__ __launch_bounds__(64) void k_conv(
    const u16* __restrict__ satTh, const u16* __restrict__ satTl,
    const u16* __restrict__ grdTh, const u16* __restrict__ grdTl,
    float* __restrict__ corr)
{
  __shared__ __align__(16) u16 ph_[36*48*8];   // hi patch [rho][px][c8]
  __shared__ __align__(16) u16 pl_[36*48*8];   // lo patch

  const int bi = blockIdx.x;
  const int xt = bi % 5;
  const int yt = (bi / 5) % 13;
  const int m  = bi / 65;
  const int y0 = yt * 5, x0 = xt * 16;

  const int lane = threadIdx.x;
  const int pr = lane & 15;        // A row index (x-position) ; also n for B loads
  const int q  = lane >> 4;        // quad -> k-subrange (filter-j offset)
  const int nn = pr & 7;           // lanes 8..15 broadcast n-8 (their D cols unused)

  floatx4 acc[5];
  #pragma unroll
  for (int r = 0; r < 5; ++r) acc[r] = (floatx4){0.f, 0.f, 0.f, 0.f};

  for (int cb = 0; cb < 4; ++cb) {
    __syncthreads();
    {
      const size_t rowbase = ((size_t)(m*4 + cb) * 96 + y0) * 96;
      for (int k = lane; k < 36*48; k += 64) {
        const int rho = k / 48;
        const int px  = k - rho*48;
        int X = x0 + px; if (X > 95) X = 95;          // clamped reads only feed masked-out outputs
        const size_t g = (rowbase + (size_t)rho*96 + X) * 8;
        *(uint4*)(&ph_[(size_t)k*8]) = *(const uint4*)(&satTh[g]);
        *(uint4*)(&pl_[(size_t)k*8]) = *(const uint4*)(&satTl[g]);
      }
    }
    __syncthreads();

    for (int jb = 0; jb < 8; ++jb) {
      const int apx = pr + jb*4 + q;                       // patch pixel (max 46)
      const u16* bh = grdTh + (size_t)cb*65536 + (size_t)(jb*4+q)*64 + (size_t)nn*8;
      const u16* bl = grdTl + (size_t)cb*65536 + (size_t)(jb*4+q)*64 + (size_t)nn*8;

      uint4 Brh[4], Brl[4];
      #pragma unroll
      for (int ii = 0; ii < 4; ++ii) {
        Brh[ii] = *(const uint4*)(bh + (size_t)ii*2048);
        Brl[ii] = *(const uint4*)(bl + (size_t)ii*2048);
      }
      uint4 Ah[8], Al[8];
      #pragma unroll
      for (int s = 0; s < 6; ++s) {
        Ah[s] = *(const uint4*)(&ph_[((size_t)s*48 + apx)*8]);
        Al[s] = *(const uint4*)(&pl_[((size_t)s*48 + apx)*8]);
      }
      #pragma unroll
      for (int i = 0; i < 32; ++i) {
        if (i < 30) {  // prefetch A rows (rho = i+6)
          Ah[(i+6)&7] = *(const uint4*)(&ph_[((size_t)(i+6)*48 + apx)*8]);
          Al[(i+6)&7] = *(const uint4*)(&pl_[((size_t)(i+6)*48 + apx)*8]);
        }
        const bf16x8 bhf = __builtin_bit_cast(bf16x8, Brh[i&3]);
        const bf16x8 blf = __builtin_bit_cast(bf16x8, Brl[i&3]);
        if (i < 28) {  // B ring prefetch, distance 4
          Brh[(i+4)&3] = *(const uint4*)(bh + (size_t)(i+4)*2048);
          Brl[(i+4)&3] = *(const uint4*)(bl + (size_t)(i+4)*2048);
        }
        #pragma unroll
        for (int r = 0; r < 5; ++r) {
          const bf16x8 ah = __builtin_bit_cast(bf16x8, Ah[(i+r)&7]);
          const bf16x8 al = __builtin_bit_cast(bf16x8, Al[(i+r)&7]);
          acc[r] = __builtin_amdgcn_mfma_f32_16x16x32_bf16(ah, bhf, acc[r], 0, 0, 0);
          acc[r] = __builtin_amdgcn_mfma_f32_16x16x32_bf16(ah, blf, acc[r], 0, 0, 0);
          acc[r] = __builtin_amdgcn_mfma_f32_16x16x32_bf16(al, bhf, acc[r], 0, 0, 0);
        }
      }
    }
  }

  // D layout: col = lane&15 = n ; row = q*4 + reg = x-offset
  if (pr < 8) {
    #pragma unroll
    for (int r = 0; r < 5; ++r) {
      const int y = y0 + r;
      #pragma unroll
      for (int e = 0; e < 4; ++e) {
        const int x = x0 + q*4 + e;
        if (x < 65)
          corr[(((size_t)m*8 + pr)*65 + y)*65 + x] = acc[r][e];
      }
    }
  }
}

// ---- K6: normalize, per-(m,n) max, diag argmax (first occurrence) ----
__global__ void k_reduce(const float* __restrict__ corr, const float* __restrict__ part,
                         const float* __restrict__ nrm, const int* __restrict__ tm,
                         float* __restrict__ out, int* __restrict__ pos) {
  const int mb = blockIdx.x;
  const int m = mb >> 3, n = mb & 7, t = threadIdx.x;
  const float srn = 1.f / fmaxf(sqrtf(nrm[8 + m]), 1e-12f);
  const float grn = 1.f / fmaxf(sqrtf(nrm[n]), 1e-12f);
  const int method = tm[0];
  const float cscale = grn * srn, pscale = srn * srn;
  float bestv = -3.4e38f; int besti = 0x7FFFFFFF;
  const float* cp = corr + (size_t)(m*8+n)*4225;
  const float* pp = part + (size_t)m*4225;
  for (int idx = t; idx < 4225; idx += 256) {
    const float partical = pp[idx] * pscale;
    float denom = (method == 0) ? sqrtf(partical) : partical;
    denom = fmaxf(denom, 1e-12f);
    const float v = cp[idx] * cscale / denom;
    if (v > bestv) { bestv = v; besti = idx; }
  }
  __shared__ float bv[256]; __shared__ int bix[256];
  bv[t] = bestv; bix[t] = besti; __syncthreads();
  for (int s = 128; s > 0; s >>= 1) {
    if (t < s) {
      const float v2 = bv[t+s]; const int i2 = bix[t+s];
      if (v2 > bv[t] || (v2 == bv[t] && i2 < bix[t])) { bv[t] = v2; bix[t] = i2; }
    }
    __syncthreads();
  }
  if (t == 0) {
    out[m*8+n] = bv[0];
    if (m == n) { pos[2*n] = bix[0] / 65; pos[2*n+1] = bix[0] - (bix[0]/65)*65; }
  }
}

// ---- K7: scatter grd_mask at argmax position ----
__global__ void k_mask(const float* __restrict__ gmask, const int* __restrict__ pos,
                       float* __restrict__ out) {
  const int n = blockIdx.x, t = threadIdx.x;
  const int ph = pos[2*n], pw = pos[2*n+1];
  for (int p = t; p < 1024; p += 256) {
    const int i = p >> 5, j = p & 31;
    out[64 + (size_t)n*9216 + (size_t)(ph+i)*96 + (pw+j)] = gmask[n*1024 + p];
  }
}

extern "C" void kernel_launch(void* const* d_in, const int* in_sizes, int n_in,
                              void* d_out, int out_size, void* d_ws, size_t ws_size,
                              hipStream_t stream) {
  const float* grd = (const float*)d_in[0];
  const float* sat = (const float*)d_in[1];
  const int*   tm  = (const int*)d_in[2];
  float* out = (float*)d_out;
  char* ws = (char*)d_ws;

  u16*   sTh  = (u16*)(ws + OFF_SATT_H);
  u16*   sTl  = (u16*)(ws + OFF_SATT_L);
  u16*   gTh  = (u16*)(ws + OFF_GRDT_H);
  u16*   gTl  = (u16*)(ws + OFF_GRDT_L);
  float* corr = (float*)(ws + OFF_CORR);
  float* s2   = (float*)(ws + OFF_S2);
  float* hs   = (float*)(ws + OFF_HS);
  float* part = (float*)(ws + OFF_PART);
  float* nrm  = (float*)(ws + OFF_NRM);
  float* gmask= (float*)(ws + OFF_MASK);
  int*   pos  = (int*)(ws + OFF_POS);

  hipMemsetAsync(d_out, 0, (size_t)out_size * sizeof(float), stream);
  hipMemsetAsync(nrm, 0, 64, stream);

  k_sat <<<288, 256, 0, stream>>>(sat, sTh, sTl, s2, nrm + 8);
  k_grd <<<8,   256, 0, stream>>>(grd, gTh, gTl, nrm, gmask);
  k_hs  <<<195, 256, 0, stream>>>(s2, hs);
  k_part<<<133, 256, 0, stream>>>(hs, part);
  k_conv<<<520, 64,  0, stream>>>(sTh, sTl, gTh, gTl, corr);
  k_reduce<<<64, 256, 0, stream>>>(corr, part, nrm, tm, out, pos);
  k_mask<<<8,   256, 0, stream>>>(gmask, pos, out);
}

// Round 2
// 187.169 us; speedup vs baseline: 3.5091x; 3.5091x over previous
//
#include <hip/hip_runtime.h>
#include <stdint.h>

typedef unsigned short u16;
typedef __bf16 bf16x8 __attribute__((ext_vector_type(8)));
typedef float floatx4 __attribute__((ext_vector_type(4)));

#define DEVI static __device__ __forceinline__

DEVI u16 f2bf(float f) {
  uint32_t u = __builtin_bit_cast(uint32_t, f);
  u += 0x7FFFu + ((u >> 16) & 1u);
  return (u16)(u >> 16);
}
DEVI float bf2f(u16 b) {
  return __builtin_bit_cast(float, (uint32_t)b << 16);
}

// ---- workspace layout (bytes) ----
static constexpr size_t OFF_SATT  = 0;                               // bf16 hi [m][cb][y][x][c8]: 8*4*96*96*8
static constexpr size_t OFF_GRDP  = OFF_SATT + (size_t)8*4*96*96*8*2;        // bf16 [cb][i][j][col16][c8] (col<8 hi(n), col>=8 lo(n-8))
static constexpr size_t OFF_CORRP = OFF_GRDP + (size_t)4*32*32*16*8*2;       // f32 [4][8][8][65][65]
static constexpr size_t OFF_S2    = OFF_CORRP + (size_t)4*270400*4;          // f32 [8][96][96]
static constexpr size_t OFF_PART  = OFF_S2   + (size_t)73728*4;              // f32 [8][65][65]
static constexpr size_t OFF_NRM   = OFF_PART + (size_t)33800*4;              // f32 grd_nrm2[8], sat_nrm2[8]
static constexpr size_t OFF_CNT   = OFF_NRM  + 64;                           // int cand count[8]
static constexpr size_t OFF_CAND  = OFF_CNT  + 32;                           // int cand[8][128]
static constexpr size_t OFF_MASK  = OFF_CAND + 4096;                         // f32 [n][1024]

// ---- K1: prep. blocks 0..287: sat slice -> bf16-hi channels-last + s2 + sat norm.
//          blocks 288..295: grd -> packed [cb][i][j][col16][c8] + norm + channel-sum mask.
__global__ void k_prep(const float* __restrict__ grd, const float* __restrict__ sat,
                       u16* __restrict__ sTh, u16* __restrict__ gP,
                       float* __restrict__ s2, float* __restrict__ nrm,
                       float* __restrict__ gmask) {
  __shared__ float red[256];
  const int t = threadIdx.x;
  if (blockIdx.x < 288) {
    const int gid = blockIdx.x * 256 + t;               // 73728 exactly
    const int m = gid / 9216;
    const int rem = gid - m * 9216;
    const int y = rem / 96;
    const int x = rem - y * 96;
    const float* src = sat + ((size_t)m*32*128 + (y+16))*128 + (x+16);
    float vals[32]; float ss = 0.f;
    #pragma unroll
    for (int c = 0; c < 32; ++c) {
      float v = src[(size_t)c * 16384];
      vals[c] = v; ss += v*v;
    }
    s2[gid] = ss;
    #pragma unroll
    for (int cb = 0; cb < 4; ++cb) {
      union { u16 us[8]; uint4 v4; } ph;
      #pragma unroll
      for (int e = 0; e < 8; ++e) ph.us[e] = f2bf(vals[cb*8+e]);
      *(uint4*)(&sTh[((size_t)(m*4+cb)*9216 + rem)*8]) = ph.v4;
    }
    red[t] = ss; __syncthreads();
    for (int s = 128; s > 0; s >>= 1) {
      if (t < s) red[t] += red[t + s];
      __syncthreads();
    }
    if (t == 0) atomicAdd(&nrm[8 + m], red[0]);
  } else {
    const int n = blockIdx.x - 288;
    float nn = 0.f, scs[4];
    #pragma unroll
    for (int it = 0; it < 4; ++it) {
      const int pidx = it*256 + t;                  // pidx = i*32 + j
      float vals[32]; float sc = 0.f;
      #pragma unroll
      for (int c = 0; c < 32; ++c) {
        float v = grd[((size_t)n*32 + c)*1024 + pidx];
        vals[c] = v; sc += v; nn += v*v;
      }
      scs[it] = sc;
      #pragma unroll
      for (int cb = 0; cb < 4; ++cb) {
        union { u16 us[8]; uint4 v4; } ph, pl;
        #pragma unroll
        for (int e = 0; e < 8; ++e) {
          float v = vals[cb*8+e];
          u16 h = f2bf(v); ph.us[e] = h; pl.us[e] = f2bf(v - bf2f(h));
        }
        const size_t o = ((size_t)cb*1024 + pidx)*128;   // [cb][i][j] * 16cols * 8c
        *(uint4*)(&gP[o + (size_t)n*8])       = ph.v4;   // col = n     : hi
        *(uint4*)(&gP[o + (size_t)(n+8)*8])   = pl.v4;   // col = n + 8 : lo
      }
    }
    red[t] = nn; __syncthreads();
    for (int s = 128; s > 0; s >>= 1) { if (t < s) red[t] += red[t+s]; __syncthreads(); }
    const float gn = fmaxf(sqrtf(red[0]), 1e-12f);
    if (t == 0) nrm[n] = red[0];
    const float thr = 1e-6f * gn;
    #pragma unroll
    for (int it = 0; it < 4; ++it)
      gmask[n*1024 + it*256 + t] = (fabsf(scs[it]) > thr) ? 1.f : 0.f;
  }
}

// ---- K2: separable 32x32 window sum of s2 (one block per m, hs kept in LDS) ----
__global__ void k_win(const float* __restrict__ s2, float* __restrict__ part) {
  __shared__ float hs[6240];          // [96][65]
  const int m = blockIdx.x, t = threadIdx.x;
  const float* sp = s2 + (size_t)m*9216;
  for (int idx = t; idx < 6240; idx += 256) {
    const int y = idx/65, xo = idx - y*65;
    const float* r = sp + y*96 + xo;
    float s = 0.f;
    #pragma unroll
    for (int j = 0; j < 32; ++j) s += r[j];
    hs[idx] = s;
  }
  __syncthreads();
  for (int idx = t; idx < 4225; idx += 256) {
    const int yo = idx/65, xo = idx - yo*65;
    float s = 0.f;
    #pragma unroll
    for (int i = 0; i < 32; ++i) s += hs[(yo+i)*65 + xo];
    part[(size_t)m*4225 + idx] = s;
  }
}

// ---- K3: conv. grid 2080 = (m,yt13,xt5,cb4); block = 4 waves splitting j (2 jb each).
// 2-term split: A = sat-hi (LDS patch), B = packed [grd-hi | grd-lo] in 16 cols.
// One MFMA per k-step; hi/lo cols combined with shfl_xor(8); cross-wave K-sum in LDS.
__global__ __launch_bounds__(256, 4) void k_conv(
    const u16* __restrict__ satT, const u16* __restrict__ gP,
    float* __restrict__ corr_p)
{
  __shared__ __align__(16) u16 patch[36*48*8];   // 27648 B, sat-hi [rho][px][c8]

  int bi = blockIdx.x;
  const int cb = bi & 3; bi >>= 2;
  const int xt = bi % 5; bi /= 5;
  const int yt = bi % 13;
  const int m  = bi / 13;
  const int y0 = yt*5, x0 = xt*16;
  const int tid = threadIdx.x;
  const int wave = tid >> 6, lane = tid & 63;

  {
    const size_t rowbase = ((size_t)(m*4 + cb) * 96 + y0) * 96;
    for (int k = tid; k < 36*48; k += 256) {
      const int rho = k / 48;
      const int px  = k - rho*48;
      int X = x0 + px; if (X > 95) X = 95;     // clamped reads feed only x>=65 outputs (never stored)
      *(uint4*)(&patch[(size_t)k*8]) = *(const uint4*)(&satT[(rowbase + (size_t)rho*96 + X)*8]);
    }
  }
  __syncthreads();

  const int pr = lane & 15;       // A row (x-offset) == B col
  const int q  = lane >> 4;

  floatx4 acc[5];
  #pragma unroll
  for (int r = 0; r < 5; ++r) acc[r] = (floatx4){0.f, 0.f, 0.f, 0.f};

  #pragma unroll
  for (int jbi = 0; jbi < 2; ++jbi) {
    const int jb = wave*2 + jbi;
    const int apx = pr + jb*4 + q;                         // <= 46
    const u16* bp = gP + ((size_t)cb*1024 + (size_t)(jb*4+q))*128 + (size_t)pr*8;

    uint4 Br[4];
    #pragma unroll
    for (int ii = 0; ii < 4; ++ii) Br[ii] = *(const uint4*)(bp + (size_t)ii*4096);
    uint4 Ah[8];
    #pragma unroll
    for (int s = 0; s < 6; ++s) Ah[s] = *(const uint4*)(&patch[((size_t)s*48 + apx)*8]);

    #pragma unroll
    for (int i = 0; i < 32; ++i) {
      if (i < 30)
        Ah[(i+6)&7] = *(const uint4*)(&patch[((size_t)(i+6)*48 + apx)*8]);
      const bf16x8 bf = __builtin_bit_cast(bf16x8, Br[i&3]);
      if (i < 28)
        Br[(i+4)&3] = *(const uint4*)(bp + (size_t)(i+4)*4096);
      #pragma unroll
      for (int r = 0; r < 5; ++r)
        acc[r] = __builtin_amdgcn_mfma_f32_16x16x32_bf16(
            __builtin_bit_cast(bf16x8, Ah[(i+r)&7]), bf, acc[r], 0, 0, 0);
    }
  }

  // combine hi (cols 0-7) + lo (cols 8-15): partner lane differs in bit 3
  float vals[20];
  #pragma unroll
  for (int r = 0; r < 5; ++r)
    #pragma unroll
    for (int e = 0; e < 4; ++e)
      vals[r*4+e] = acc[r][e] + __shfl_xor(acc[r][e], 8);

  // cross-wave K-sum (4 waves = j-octets) via LDS, then wave 0 stores cb-partial
  __syncthreads();
  float* red = (float*)patch;                    // 4*64*21*4 = 21504 B <= 27648
  #pragma unroll
  for (int u = 0; u < 20; ++u) red[((size_t)wave*64 + lane)*21 + u] = vals[u];
  __syncthreads();
  if (wave == 0 && pr < 8) {
    #pragma unroll
    for (int r = 0; r < 5; ++r) {
      #pragma unroll
      for (int e = 0; e < 4; ++e) {
        const int x = x0 + q*4 + e;
        if (x < 65) {
          float s = 0.f;
          #pragma unroll
          for (int w = 0; w < 4; ++w) s += red[((size_t)w*64 + lane)*21 + r*4 + e];
          corr_p[(size_t)cb*270400 + ((size_t)(m*8+pr)*65 + (y0+r))*65 + x] = s;
        }
      }
    }
  }
}

// ---- K4: normalize, per-(m,n) max -> similarity; diag: collect candidates near max ----
__global__ void k_reduce(const float* __restrict__ corr_p, const float* __restrict__ part,
                         const float* __restrict__ nrm, const int* __restrict__ tm,
                         float* __restrict__ out, int* __restrict__ cnt,
                         int* __restrict__ cand) {
  const int mb = blockIdx.x;
  const int m = mb >> 3, n = mb & 7, t = threadIdx.x;
  const float srn = 1.f / fmaxf(sqrtf(nrm[8 + m]), 1e-12f);
  const float grn = 1.f / fmaxf(sqrtf(nrm[n]), 1e-12f);
  const int method = tm[0];
  const float cscale = grn * srn, pscale = srn * srn;
  const float* cp = corr_p + (size_t)(m*8+n)*4225;
  const float* pp = part + (size_t)m*4225;
  float bestv = -3.4e38f;
  for (int idx = t; idx < 4225; idx += 256) {
    const float c = cp[idx] + cp[idx+270400] + cp[idx+540800] + cp[idx+811200];
    const float partical = pp[idx] * pscale;
    float denom = (method == 0) ? sqrtf(partical) : partical;
    denom = fmaxf(denom, 1e-12f);
    const float v = c * cscale / denom;
    if (v > bestv) bestv = v;
  }
  __shared__ float bv[256];
  bv[t] = bestv; __syncthreads();
  for (int s = 128; s > 0; s >>= 1) {
    if (t < s) bv[t] = fmaxf(bv[t], bv[t+s]);
    __syncthreads();
  }
  if (t == 0) out[m*8+n] = bv[0];
  if (m == n) {
    const float thr2 = bv[0] - 5e-4f;     // ~23 sigma of the 2-term split error
    for (int idx = t; idx < 4225; idx += 256) {
      const float c = cp[idx] + cp[idx+270400] + cp[idx+540800] + cp[idx+811200];
      const float partical = pp[idx] * pscale;
      float denom = (method == 0) ? sqrtf(partical) : partical;
      denom = fmaxf(denom, 1e-12f);
      const float v = c * cscale / denom;
      if (v >= thr2) {
        const int s = atomicAdd(&cnt[n], 1);
        if (s < 128) cand[n*128 + s] = idx;
      }
    }
  }
}

// ---- K5: exact fp32 re-dot of diag candidates, true argmax, mask scatter ----
__global__ void k_refine(const float* __restrict__ grd, const float* __restrict__ sat,
                         const float* __restrict__ part, const float* __restrict__ nrm,
                         const int* __restrict__ tm, const int* __restrict__ cnt,
                         const int* __restrict__ cand, const float* __restrict__ gmask,
                         float* __restrict__ out) {
  const int n = blockIdx.x, t = threadIdx.x;
  const float srn = 1.f / fmaxf(sqrtf(nrm[8 + n]), 1e-12f);
  const float grn = 1.f / fmaxf(sqrtf(nrm[n]), 1e-12f);
  const float cscale = grn * srn, pscale = srn * srn;
  const int method = tm[0];
  int nc = cnt[n]; if (nc > 128) nc = 128; if (nc < 1) nc = 1;
  __shared__ float red[256];
  __shared__ float sbest; __shared__ int sbix;
  __shared__ int sph, spw;
  if (t == 0) { sbest = -3.4e38f; sbix = 0x7FFFFFFF; }
  __syncthreads();
  const int c = t >> 3, s8 = t & 7;
  for (int ci = 0; ci < nc; ++ci) {
    const int idx = cand[n*128 + ci];
    const int y = idx / 65, x = idx - y*65;
    float a = 0.f;
    #pragma unroll
    for (int ii = 0; ii < 4; ++ii) {
      const int i = s8 + ii*8;
      const float* gr = grd + ((size_t)n*32 + c)*1024 + i*32;
      const float* sr = sat + (((size_t)n*32 + c)*128 + (16 + y + i))*128 + (16 + x);
      #pragma unroll
      for (int j = 0; j < 32; ++j) a += gr[j] * sr[j];
    }
    red[t] = a; __syncthreads();
    for (int st = 128; st > 0; st >>= 1) {
      if (t < st) red[t] += red[t+st];
      __syncthreads();
    }
    if (t == 0) {
      const float partical = part[(size_t)n*4225 + idx] * pscale;
      float denom = (method == 0) ? sqrtf(partical) : partical;
      denom = fmaxf(denom, 1e-12f);
      const float v = red[0] * cscale / denom;
      if (v > sbest || (v == sbest && idx < sbix)) { sbest = v; sbix = idx; }
    }
    __syncthreads();
  }
  if (t == 0) { sph = sbix / 65; spw = sbix - (sbix/65)*65; }
  __syncthreads();
  const int ph = sph, pw = spw;
  for (int p = t; p < 1024; p += 256)
    out[64 + (size_t)n*9216 + (size_t)(ph + (p>>5))*96 + (pw + (p&31))] = gmask[n*1024 + p];
}

extern "C" void kernel_launch(void* const* d_in, const int* in_sizes, int n_in,
                              void* d_out, int out_size, void* d_ws, size_t ws_size,
                              hipStream_t stream) {
  const float* grd = (const float*)d_in[0];
  const float* sat = (const float*)d_in[1];
  const int*   tm  = (const int*)d_in[2];
  float* out = (float*)d_out;
  char* ws = (char*)d_ws;

  u16*   sTh   = (u16*)(ws + OFF_SATT);
  u16*   gP    = (u16*)(ws + OFF_GRDP);
  float* corrp = (float*)(ws + OFF_CORRP);
  float* s2    = (float*)(ws + OFF_S2);
  float* part  = (float*)(ws + OFF_PART);
  float* nrm   = (float*)(ws + OFF_NRM);
  int*   cnt   = (int*)(ws + OFF_CNT);
  int*   cand  = (int*)(ws + OFF_CAND);
  float* gmask = (float*)(ws + OFF_MASK);

  hipMemsetAsync(d_out, 0, (size_t)out_size * sizeof(float), stream);
  hipMemsetAsync(nrm, 0, 96, stream);   // nrm[16] + cnt[8]

  k_prep  <<<296,  256, 0, stream>>>(grd, sat, sTh, gP, s2, nrm, gmask);
  k_win   <<<8,    256, 0, stream>>>(s2, part);
  k_conv  <<<2080, 256, 0, stream>>>(sTh, gP, corrp);
  k_reduce<<<64,   256, 0, stream>>>(corrp, part, nrm, tm, out, cnt, cand);
  k_refine<<<8,    256, 0, stream>>>(grd, sat, part, nrm, tm, cnt, cand, gmask, out);
}